// Round 5
// baseline (332.211 us; speedup 1.0000x reference)
//
#include <hip/hip_runtime.h>
#include <math.h>

#define BB 8
#define CC 128
#define N0 4096
#define MSGN 4
#define NTOT 4100
#define IMG 64
#define NPAD 4112
#define QTILES 257
#define LMP1 320
#define LMP2 1088

// ---------------- workspace layout (float indices) ----------------
#define OFF_WFQ    0
#define OFF_WFKV1  8192
#define OFF_WFKV2  16384
#define OFF_WFPROJ 24576
#define OFF_WFSR1  32768        // K=2048: 131072 f
#define OFF_WFSR2  163840       // K=512:  32768 f
#define OFF_QH     196608       // fp16 8*4*4112*32 = 2105344 f
#define OFF_XA     2301952      // qproj A-frags / attn-out A-frags: 2101248 f
#define OFF_XIM    4403200      // im2col A-frags, max 2112*2048 h = 2162688 f
#define OFF_XK1    6565888      // LN+GELU out A-frags 2112*128 h = 135168 f
#define OFF_XK2    6701056      // 8256*128 h = 528384 f
#define OFF_KV1O   7229440      // fp32 8*260*128 = 266240 f
#define OFF_KV2O   7495680      // fp32 8*1028*128 = 1052672 f
#define OFF_KH1    8548352      // fp16 8*2*320*32 = 81920 f
#define OFF_VT1    8630272      // 81920 f
#define OFF_KH2    8712192      // fp16 8*2*1088*32 = 278528 f
#define OFF_VT2    8990720      // 278528 f ; end 9269248 f = 37.1 MB

typedef _Float16 half8v __attribute__((ext_vector_type(8)));
typedef _Float16 half4v __attribute__((ext_vector_type(4)));
typedef float f32x4 __attribute__((ext_vector_type(4)));

__device__ __forceinline__ size_t af_idx(int m, int k, int Kc) {
    return ((size_t)((m >> 4) * Kc + (k >> 5)) * 64 + ((k >> 3) & 3) * 16 + (m & 15)) * 8 + (k & 7);
}

// ---------------- weight prep: swizzle into B-fragment order ----------------
__global__ void prep_weights(const float* __restrict__ Wq, const float* __restrict__ kv1,
                             const float* __restrict__ kv2, const float* __restrict__ proj,
                             const float* __restrict__ sr1w, const float* __restrict__ sr2w,
                             float* __restrict__ ws) {
    int u = blockIdx.x * blockDim.x + threadIdx.x;   // 49152 units
    int seg, base;
    const float* w = nullptr;
    _Float16* dst;
    if (u < 2048)        { seg = 0; base = u;          w = Wq;   dst = (_Float16*)(ws + OFF_WFQ); }
    else if (u < 4096)   { seg = 0; base = u - 2048;   w = kv1;  dst = (_Float16*)(ws + OFF_WFKV1); }
    else if (u < 6144)   { seg = 0; base = u - 4096;   w = kv2;  dst = (_Float16*)(ws + OFF_WFKV2); }
    else if (u < 8192)   { seg = 0; base = u - 6144;   w = proj; dst = (_Float16*)(ws + OFF_WFPROJ); }
    else if (u < 40960)  { seg = 1; base = u - 8192;   w = sr1w; dst = (_Float16*)(ws + OFF_WFSR1); }
    else if (u < 49152)  { seg = 2; base = u - 40960;  w = sr2w; dst = (_Float16*)(ws + OFF_WFSR2); }
    else return;
    int lane = base & 63;
    int t = (base >> 6) & 7;
    int kc = base >> 9;
    int n = t * 16 + (lane & 15);
    int k0 = kc * 32 + (lane >> 4) * 8;
    half8v val;
    #pragma unroll
    for (int j = 0; j < 8; ++j) {
        int k = k0 + j;
        float v;
        if (seg == 0) v = w[n * 128 + k];
        else if (seg == 1) v = w[(n * 128 + (k & 127)) * 16 + (k >> 7)];
        else v = w[(n * 128 + (k & 127)) * 4 + (k >> 7)];
        val[j] = (_Float16)v;
    }
    *(half8v*)(dst + (size_t)base * 8) = val;
}

// ---------------- convert x||msg -> A-frag fp16 (K=128) ----------------
__global__ void convert_x(const float* __restrict__ x, const float* __restrict__ msg,
                          _Float16* __restrict__ Af) {
    int u = blockIdx.x * blockDim.x + threadIdx.x;    // 525312 units
    if (u >= 525312) return;
    int mlow = u & 15, quadk = (u >> 4) & 3;
    int rest = u >> 6;
    int kc = rest & 3;      // Kc = 4
    int mt = rest >> 2;
    int m = mt * 16 + mlow;
    int c0 = (kc * 4 + quadk) * 8;
    half8v val;
    if (m < BB * NTOT) {
        int b = m / NTOT, n = m - b * NTOT;
        const float* p = (n < N0) ? (x + ((size_t)b * N0 + n) * 128 + c0)
                                  : (msg + ((size_t)b * MSGN + (n - N0)) * 128 + c0);
        #pragma unroll
        for (int j = 0; j < 8; ++j) val[j] = (_Float16)p[j];
    } else {
        #pragma unroll
        for (int j = 0; j < 8; ++j) val[j] = (_Float16)0.f;
    }
    *(half8v*)(Af + (size_t)u * 8) = val;
}

// ---------------- im2col (pure permutation: stride == patch size) ----------------
__global__ void im2col(const float* __restrict__ x, const float* __restrict__ msg,
                       _Float16* __restrict__ Af, int s, int Wr, int L, int Lm,
                       int Kc, int nunits) {
    int u = blockIdx.x * blockDim.x + threadIdx.x;
    if (u >= nunits) return;
    int mlow = u & 15, quadk = (u >> 4) & 3;
    int rest = u >> 6;
    int kc = rest % Kc;
    int mt = rest / Kc;
    int m = mt * 16 + mlow;
    int k0 = (kc * 4 + quadk) * 8;
    half8v val;
    if (m < BB * Lm) {
        int b = m / Lm, tok = m - b * Lm;
        int ij = k0 >> 7, c = k0 & 127;
        const float* p;
        if (tok < L) {
            int hr = tok / Wr, wr = tok - hr * Wr;
            int ki = ij / s, kj = ij - ki * s;
            int pix = (hr * s + ki) * IMG + (wr * s + kj);
            p = x + ((size_t)b * N0 + pix) * 128 + c;
        } else {
            p = msg + ((size_t)b * MSGN + (tok - L)) * 128 + c;
        }
        #pragma unroll
        for (int j = 0; j < 8; ++j) val[j] = (_Float16)p[j];
    } else {
        #pragma unroll
        for (int j = 0; j < 8; ++j) val[j] = (_Float16)0.f;
    }
    *(half8v*)(Af + (size_t)u * 8) = val;
}

// zero fp16 Q pad rows (queries 4100..4111)
__global__ void zero_qpad(_Float16* __restrict__ Qh) {
    int idx = blockIdx.x * blockDim.x + threadIdx.x;
    if (idx >= BB * 4 * (NPAD - NTOT) * 32) return;
    int d = idx & 31;
    int rest = idx >> 5;
    int n = NTOT + rest % (NPAD - NTOT);
    int rest2 = rest / (NPAD - NTOT);
    int hg = rest2 & 3;
    int b = rest2 >> 2;
    Qh[((size_t)(b * 4 + hg) * NPAD + n) * 32 + d] = (_Float16)0.f;
}

// ---------------- unified MFMA gemm: [M x K] * [K x 128] ----------------
// mode 0: +bias, *1/sqrt(32) -> Qh fp16 attention layout
// mode 1: +bias -> fp32 row-major (kv)
// mode 2: +bias, LN(g,b), GELU -> A-frag fp16
// mode 3: +bias, +residual(x,msg) -> d_out split fp32
__global__ __launch_bounds__(256) void gemm_mfma(
    const _Float16* __restrict__ Af, const _Float16* __restrict__ Wf,
    const float* __restrict__ bias, int K, int Mvalid, int mode,
    float* __restrict__ out_f32, _Float16* __restrict__ out_f16,
    const float* __restrict__ ln_g, const float* __restrict__ ln_b,
    const float* __restrict__ x, const float* __restrict__ msg) {
    int lane = threadIdx.x & 63, wave = threadIdx.x >> 6;
    int mt = blockIdx.x * 4 + wave;
    int Kc = K >> 5;
    const half8v* Ap = (const half8v*)Af + (size_t)mt * Kc * 64 + lane;
    const half8v* Bp = (const half8v*)Wf + lane;
    f32x4 acc[8];
    #pragma unroll
    for (int t = 0; t < 8; ++t) acc[t] = (f32x4){0.f, 0.f, 0.f, 0.f};
    for (int kc = 0; kc < Kc; ++kc) {
        half8v a = Ap[(size_t)kc * 64];
        #pragma unroll
        for (int t = 0; t < 8; ++t) {
            half8v b = Bp[(size_t)(kc * 8 + t) * 64];
            acc[t] = __builtin_amdgcn_mfma_f32_16x16x32_f16(a, b, acc[t], 0, 0, 0);
        }
    }
    int quad = lane >> 4, n15 = lane & 15;
    float bs[8];
    #pragma unroll
    for (int t = 0; t < 8; ++t) bs[t] = bias[t * 16 + n15];

    if (mode == 2) {
        #pragma unroll
        for (int r = 0; r < 4; ++r) {
            int m = mt * 16 + quad * 4 + r;
            float v[8];
            float s = 0.f;
            #pragma unroll
            for (int t = 0; t < 8; ++t) { v[t] = acc[t][r] + bs[t]; s += v[t]; }
            #pragma unroll
            for (int off = 1; off < 16; off <<= 1) s += __shfl_xor(s, off);
            float mu = s * (1.f / 128.f);
            float q = 0.f;
            #pragma unroll
            for (int t = 0; t < 8; ++t) { v[t] -= mu; q += v[t] * v[t]; }
            #pragma unroll
            for (int off = 1; off < 16; off <<= 1) q += __shfl_xor(q, off);
            float rs = rsqrtf(q * (1.f / 128.f) + 1e-5f);
            if (m < Mvalid) {
                #pragma unroll
                for (int t = 0; t < 8; ++t) {
                    int n = t * 16 + n15;
                    float y = v[t] * rs * ln_g[n] + ln_b[n];
                    y = 0.5f * y * (1.f + erff(y * 0.70710678118654752f));
                    out_f16[af_idx(m, n, 4)] = (_Float16)y;
                }
            }
        }
    } else if (mode == 1) {
        #pragma unroll
        for (int r = 0; r < 4; ++r) {
            int m = mt * 16 + quad * 4 + r;
            if (m >= Mvalid) continue;
            #pragma unroll
            for (int t = 0; t < 8; ++t)
                out_f32[(size_t)m * 128 + t * 16 + n15] = acc[t][r] + bs[t];
        }
    } else if (mode == 0) {
        const float qscale = 0.17677669529663687f;   // 1/sqrt(32), folded into Q
        #pragma unroll
        for (int r = 0; r < 4; ++r) {
            int m = mt * 16 + quad * 4 + r;
            if (m >= Mvalid) continue;
            int b = m / NTOT, tok = m - b * NTOT;
            #pragma unroll
            for (int t = 0; t < 8; ++t) {
                int n = t * 16 + n15;
                out_f16[((size_t)(b * 4 + (n >> 5)) * NPAD + tok) * 32 + (n & 31)] =
                    (_Float16)((acc[t][r] + bs[t]) * qscale);
            }
        }
    } else {
        #pragma unroll
        for (int r = 0; r < 4; ++r) {
            int m = mt * 16 + quad * 4 + r;
            if (m >= Mvalid) continue;
            int b = m / NTOT, tok = m - b * NTOT;
            const float* rp;
            float* dst;
            if (tok < N0) {
                rp = x + ((size_t)b * N0 + tok) * 128;
                dst = out_f32 + ((size_t)b * N0 + tok) * 128;
            } else {
                rp = msg + ((size_t)b * MSGN + (tok - N0)) * 128;
                dst = out_f32 + (size_t)BB * N0 * 128 + ((size_t)b * MSGN + (tok - N0)) * 128;
            }
            #pragma unroll
            for (int t = 0; t < 8; ++t) {
                int n = t * 16 + n15;
                dst[n] = acc[t][r] + bs[t] + rp[n];
            }
        }
    }
}

// ---------------- fused V-fixup + fp16 pack (zero-pads n in [Lm, Lmp)) ----------------
__global__ void pack_kv(const float* __restrict__ kv, const float* __restrict__ lcw,
                        const float* __restrict__ lcb, _Float16* __restrict__ Kh,
                        _Float16* __restrict__ Vt, int Wr, int L, int Lm, int Lmp) {
    int idx = blockIdx.x * blockDim.x + threadIdx.x;
    int total = BB * Lmp * 64;
    if (idx >= total) return;
    int ch = idx & 63;
    int rest = idx >> 6;
    int n = rest % Lmp;
    int b = rest / Lmp;
    int h2 = ch >> 5, d = ch & 31;
    int Hr = L / Wr;
    float kval = 0.f, vnew = 0.f;
    if (n < Lm) {
        const float* kvb = kv + (size_t)b * Lm * 128;
        kval = kvb[(size_t)n * 128 + ch];
        float v = kvb[(size_t)n * 128 + 64 + ch];
        float add;
        if (n < L) {
            int hr = n / Wr, wr = n - hr * Wr;
            float sum = lcb[ch];
            #pragma unroll
            for (int ki = 0; ki < 3; ++ki)
                #pragma unroll
                for (int kj = 0; kj < 3; ++kj) {
                    int y = hr + ki - 1, xx = wr + kj - 1;
                    if ((unsigned)y < (unsigned)Hr && (unsigned)xx < (unsigned)Wr)
                        sum += lcw[ch * 9 + ki * 3 + kj] * kvb[((size_t)y * Wr + xx) * 128 + 64 + ch];
                }
            add = sum;
        } else {
            add = v;   // msg tokens: v_add = v => v_new = 2v
        }
        vnew = v + add;
    }
    Kh[((size_t)(b * 2 + h2) * Lmp + n) * 32 + d] = (_Float16)kval;
    Vt[((size_t)(b * 2 + h2) * 32 + d) * Lmp + n] = (_Float16)vnew;
}

// ---------------- merged MFMA flash attention: 64-key chunks, explicit masking ----------------
__global__ __launch_bounds__(256) void attn_mfma(
    const _Float16* __restrict__ Qh,
    const _Float16* __restrict__ Kh1, const _Float16* __restrict__ Vt1,
    const _Float16* __restrict__ Kh2, const _Float16* __restrict__ Vt2,
    _Float16* __restrict__ xcat) {
    int tid = threadIdx.x;
    int lane = tid & 63, wave = tid >> 6;
    int b = blockIdx.y;
    int z = blockIdx.z;
    int br = z >> 1, h2 = z & 1;
    int tile = blockIdx.x * 4 + wave;
    if (tile >= QTILES) return;
    int Lm = br ? 1028 : 260;
    int Lmp = br ? LMP2 : LMP1;
    const _Float16* kb = (br ? Kh2 : Kh1) + (size_t)(b * 2 + h2) * Lmp * 32;
    const _Float16* vb = (br ? Vt2 : Vt1) + (size_t)(b * 2 + h2) * 32 * Lmp;
    int n0 = tile * 16;
    int q16 = lane & 15, quad = lane >> 4;
    int hg = br * 2 + h2;

    half8v qf = *(const half8v*)(Qh + ((size_t)(b * 4 + hg) * NPAD + n0 + q16) * 32 + quad * 8);
    f32x4 O0 = {0.f, 0.f, 0.f, 0.f}, O1 = {0.f, 0.f, 0.f, 0.f};
    float m_run = -1e30f, l_part = 0.f;
    const f32x4 zf = {0.f, 0.f, 0.f, 0.f};

    for (int k0 = 0; k0 < Lmp; k0 += 64) {
        f32x4 s4[4];
        #pragma unroll
        for (int i = 0; i < 4; ++i) {
            half8v kf = *(const half8v*)(kb + (size_t)(k0 + i * 16 + q16) * 32 + quad * 8);
            s4[i] = __builtin_amdgcn_mfma_f32_16x16x32_f16(kf, qf, zf, 0, 0, 0);
        }
        // explicit mask (scale already folded into Q)
        float sc[4][4];
        float mx = -1e30f;
        #pragma unroll
        for (int i = 0; i < 4; ++i)
            #pragma unroll
            for (int r = 0; r < 4; ++r) {
                int key = k0 + i * 16 + quad * 4 + r;
                sc[i][r] = (key < Lm) ? s4[i][r] : -1e30f;
                mx = fmaxf(mx, sc[i][r]);
            }
        mx = fmaxf(mx, __shfl_xor(mx, 16));
        mx = fmaxf(mx, __shfl_xor(mx, 32));
        float mnew = fmaxf(m_run, mx);
        float alpha = __expf(m_run - mnew);
        m_run = mnew;
        float ps = 0.f;
        half4v pf[4];
        #pragma unroll
        for (int i = 0; i < 4; ++i)
            #pragma unroll
            for (int r = 0; r < 4; ++r) {
                float p = __expf(sc[i][r] - mnew);
                ps += p;
                pf[i][r] = (_Float16)p;
            }
        l_part = l_part * alpha + ps;
        #pragma unroll
        for (int r = 0; r < 4; ++r) {
            float ar = __shfl(alpha, quad * 4 + r);
            O0[r] *= ar;
            O1[r] *= ar;
        }
        #pragma unroll
        for (int i = 0; i < 4; ++i) {
            int kq = k0 + i * 16 + quad * 4;
            half4v v0 = *(const half4v*)(vb + (size_t)q16 * Lmp + kq);
            half4v v1 = *(const half4v*)(vb + (size_t)(16 + q16) * Lmp + kq);
            O0 = __builtin_amdgcn_mfma_f32_16x16x16f16(pf[i], v0, O0, 0, 0, 0);
            O1 = __builtin_amdgcn_mfma_f32_16x16x16f16(pf[i], v1, O1, 0, 0, 0);
        }
    }

    float l = l_part;
    l += __shfl_xor(l, 16);
    l += __shfl_xor(l, 32);
    float invl = 1.f / l;
    int kbase = br * 64 + h2 * 32;
    #pragma unroll
    for (int r = 0; r < 4; ++r) {
        float ir = __shfl(invl, quad * 4 + r);
        int n = n0 + quad * 4 + r;
        if (n < NTOT) {
            int m = b * NTOT + n;
            xcat[af_idx(m, kbase + q16, 4)] = (_Float16)(O0[r] * ir);
            xcat[af_idx(m, kbase + 16 + q16, 4)] = (_Float16)(O1[r] * ir);
        }
    }
}

extern "C" void kernel_launch(void* const* d_in, const int* in_sizes, int n_in,
                              void* d_out, int out_size, void* d_ws, size_t ws_size,
                              hipStream_t stream) {
    const float* x     = (const float*)d_in[0];
    const float* msg   = (const float*)d_in[1];
    const float* Wq    = (const float*)d_in[2];
    const float* bq    = (const float*)d_in[3];
    const float* sr1w  = (const float*)d_in[4];
    const float* sr1b  = (const float*)d_in[5];
    const float* ln1g  = (const float*)d_in[6];
    const float* ln1b  = (const float*)d_in[7];
    const float* sr2w  = (const float*)d_in[8];
    const float* sr2b  = (const float*)d_in[9];
    const float* ln2g  = (const float*)d_in[10];
    const float* ln2b  = (const float*)d_in[11];
    const float* kv1w  = (const float*)d_in[12];
    const float* kv1b  = (const float*)d_in[13];
    const float* kv2w  = (const float*)d_in[14];
    const float* kv2b  = (const float*)d_in[15];
    const float* lc1w  = (const float*)d_in[16];
    const float* lc1b  = (const float*)d_in[17];
    const float* lc2w  = (const float*)d_in[18];
    const float* lc2b  = (const float*)d_in[19];
    const float* projw = (const float*)d_in[20];
    const float* projb = (const float*)d_in[21];
    float* ws  = (float*)d_ws;
    float* out = (float*)d_out;

    _Float16* WfQ    = (_Float16*)(ws + OFF_WFQ);
    _Float16* WfKV1  = (_Float16*)(ws + OFF_WFKV1);
    _Float16* WfKV2  = (_Float16*)(ws + OFF_WFKV2);
    _Float16* WfPROJ = (_Float16*)(ws + OFF_WFPROJ);
    _Float16* WfSR1  = (_Float16*)(ws + OFF_WFSR1);
    _Float16* WfSR2  = (_Float16*)(ws + OFF_WFSR2);
    _Float16* Qh     = (_Float16*)(ws + OFF_QH);
    _Float16* XA     = (_Float16*)(ws + OFF_XA);
    _Float16* XIM    = (_Float16*)(ws + OFF_XIM);
    _Float16* XK1    = (_Float16*)(ws + OFF_XK1);
    _Float16* XK2    = (_Float16*)(ws + OFF_XK2);
    float* kv1o      = ws + OFF_KV1O;
    float* kv2o      = ws + OFF_KV2O;
    _Float16* Kh1    = (_Float16*)(ws + OFF_KH1);
    _Float16* Vt1    = (_Float16*)(ws + OFF_VT1);
    _Float16* Kh2    = (_Float16*)(ws + OFF_KH2);
    _Float16* Vt2    = (_Float16*)(ws + OFF_VT2);

    prep_weights<<<192, 256, 0, stream>>>(Wq, kv1w, kv2w, projw, sr1w, sr2w, ws);
    zero_qpad<<<48, 256, 0, stream>>>(Qh);
    convert_x<<<2052, 256, 0, stream>>>(x, msg, XA);

    // q projection: M=32800, K=128 -> Qh fp16 (1/sqrt(32) folded in)
    gemm_mfma<<<513, 256, 0, stream>>>(XA, WfQ, bq, 128, BB * NTOT, 0,
                                       nullptr, Qh, nullptr, nullptr, nullptr, nullptr);

    // ---- branch 1 (stride 4, L=256, Lm=260, Lmp=320, K=2048) ----
    im2col<<<2112, 256, 0, stream>>>(x, msg, XIM, 4, 16, 256, 260, 64, 540672);
    gemm_mfma<<<33, 256, 0, stream>>>(XIM, WfSR1, sr1b, 2048, BB * 260, 2,
                                      nullptr, XK1, ln1g, ln1b, nullptr, nullptr);
    gemm_mfma<<<33, 256, 0, stream>>>(XK1, WfKV1, kv1b, 128, BB * 260, 1,
                                      kv1o, nullptr, nullptr, nullptr, nullptr, nullptr);
    pack_kv<<<640, 256, 0, stream>>>(kv1o, lc1w, lc1b, Kh1, Vt1, 16, 256, 260, LMP1);

    // ---- branch 2 (stride 2, L=1024, Lm=1028, Lmp=1088, K=512) ----
    im2col<<<2064, 256, 0, stream>>>(x, msg, XIM, 2, 32, 1024, 1028, 16, 528384);
    gemm_mfma<<<129, 256, 0, stream>>>(XIM, WfSR2, sr2b, 512, BB * 1028, 2,
                                       nullptr, XK2, ln2g, ln2b, nullptr, nullptr);
    gemm_mfma<<<129, 256, 0, stream>>>(XK2, WfKV2, kv2b, 128, BB * 1028, 1,
                                       kv2o, nullptr, nullptr, nullptr, nullptr, nullptr);
    pack_kv<<<2176, 256, 0, stream>>>(kv2o, lc2w, lc2b, Kh2, Vt2, 32, 1024, 1028, LMP2);

    // merged flash attention (both branches, both half-head groups)
    attn_mfma<<<dim3(65, 8, 4), 256, 0, stream>>>(Qh, Kh1, Vt1, Kh2, Vt2, XA);

    // final projection + residual -> d_out (split)
    gemm_mfma<<<513, 256, 0, stream>>>(XA, WfPROJ, projb, 128, BB * NTOT, 3,
                                       out, nullptr, nullptr, nullptr, x, msg);
}